// Round 1
// baseline (142.414 us; speedup 1.0000x reference)
//
#include <hip/hip_runtime.h>

// HeadlessAttention: B=2, K=512, Q=512, T=128
//
// k = key@Wk^T; q = query@Wq^T; v = value@Wv^T
// logits[b,kk,q,u] = sum_t k[b,kk,t]*q[b,q,t]*Wl[u,t]
//                  = (Q_hat[b] @ diag(k[b,kk,:]) Wl^T)[q,u]
// swishmax over q (per b,kk,u); out = (sum_kk v[kk,u]*scale) @ Wo^T
//
// Trick: store k pre-scaled by log2e -> logits y = log2e * x; then
//   xexp = x*exp(x-m) = (1/c)*w with w = y*2^(y-my), c = log2e
//   scale = w / (sum_q |w| + c)        (native v_exp_f32, no extra muls)

using f16    = _Float16;
using f16x8  = __attribute__((ext_vector_type(8)))  f16;
using f32x16 = __attribute__((ext_vector_type(16))) float;

#define LOG2E 1.4426950408889634f

__device__ __forceinline__ float exp2_fast(float x) {
  float r;
  asm("v_exp_f32 %0, %1" : "=v"(r) : "v"(x));
  return r;
}

__device__ __forceinline__ f16x8 cvt8(float4 a, float4 b) {
  f16x8 r;
  r[0]=(f16)a.x; r[1]=(f16)a.y; r[2]=(f16)a.z; r[3]=(f16)a.w;
  r[4]=(f16)b.x; r[5]=(f16)b.y; r[6]=(f16)b.z; r[7]=(f16)b.w;
  return r;
}

// ---------------- K1: q,k,v projections (lin(x,W) = x @ W^T) ----------------
// grid 48 = 3 tensors x B(2) x 8 row-tiles of 64. 256 thr = 4 waves,
// wave: 32 rows x 64 cols via 2x mfma_f32_32x32x16_f16 per k-chunk.
__global__ __launch_bounds__(256, 2) void k1_proj(
    const float* __restrict__ q_tok, const float* __restrict__ k_tok,
    const float* __restrict__ v_tok, const float* __restrict__ Wq,
    const float* __restrict__ Wk,    const float* __restrict__ Wv,
    f16* __restrict__ qh, float* __restrict__ kls, float* __restrict__ vf)
{
  const int gid    = blockIdx.x;        // 0..47
  const int tensor = gid >> 4;          // 0=q 1=k 2=v
  const int sub    = gid & 15;
  const int b      = sub >> 3;
  const int rt     = sub & 7;
  const float* X = tensor==0 ? q_tok : (tensor==1 ? k_tok : v_tok);
  const float* W = tensor==0 ? Wq    : (tensor==1 ? Wk    : Wv);

  const int tid = threadIdx.x;
  const int w = tid >> 6, lane = tid & 63;
  const int l31 = lane & 31, lhi = lane >> 5;
  const int rbase = rt*64 + (w>>1)*32;
  const int cbase = (w&1)*64;

  f32x16 C0, C1;
  #pragma unroll
  for (int i=0;i<16;++i){ C0[i]=0.f; C1[i]=0.f; }

  #pragma unroll
  for (int kc=0; kc<8; ++kc) {
    const float* ap = X + (size_t)(b*512 + rbase + l31)*128 + kc*16 + 8*lhi;
    f16x8 a = cvt8(*(const float4*)ap, *(const float4*)(ap+4));
    const float* bp0 = W + (size_t)(cbase + l31)*128 + kc*16 + 8*lhi;
    f16x8 b0 = cvt8(*(const float4*)bp0, *(const float4*)(bp0+4));
    C0 = __builtin_amdgcn_mfma_f32_32x32x16_f16(a, b0, C0, 0, 0, 0);
    const float* bp1 = bp0 + 32*128;
    f16x8 b1 = cvt8(*(const float4*)bp1, *(const float4*)(bp1+4));
    C1 = __builtin_amdgcn_mfma_f32_32x32x16_f16(a, b1, C1, 0, 0, 0);
  }

  #pragma unroll
  for (int us=0; us<2; ++us) {
    #pragma unroll
    for (int r=0; r<16; ++r) {
      const int row = rbase + (r&3) + 8*(r>>2) + 4*lhi;   // verified C/D layout
      const int col = cbase + us*32 + l31;
      const float val = us ? C1[r] : C0[r];
      const size_t idx = (size_t)(b*512 + row)*128 + col;
      if (tensor==0)      qh[idx]  = (f16)val;
      else if (tensor==1) kls[idx] = val * LOG2E;   // fold log2e into k
      else                vf[idx]  = val;
    }
  }
}

// ---------------- K2: fused logits + swishmax + v-scale + K-accumulate ------
// grid 256 = b(2) x u-half(2) x kk-group(64, 8 kk each). 512 thr = 8 waves.
// Wave w: q rows [64w,64w+64) x 64 u cols. A-frags (q_hat) register-resident.
__global__ __launch_bounds__(512, 2) void k2_main(
    const f16* __restrict__ qh, const float* __restrict__ kls,
    const float* __restrict__ vf, const float* __restrict__ Wl,
    float* __restrict__ vsum)
{
  const int gid  = blockIdx.x;          // 0..255
  const int b    = gid >> 7;
  const int half = (gid >> 6) & 1;
  const int grp  = gid & 63;
  const int kk0  = grp * 8;

  const int tid = threadIdx.x;
  const int w = tid >> 6, lane = tid & 63;
  const int l31 = lane & 31, lhi = lane >> 5;
  const int ubase = half * 64;
  const int qbase = w * 64;

  __shared__ f16   Bl[64][136];     // [u][t] scaled Wl, +8 pad (bank spread)
  __shared__ float redm[8][64];
  __shared__ float reds[8][64];

  // ---- A fragments: q_hat rows, held in registers the whole kernel
  f16x8 af[2][8];
  #pragma unroll
  for (int qs=0; qs<2; ++qs)
    #pragma unroll
    for (int kc=0; kc<8; ++kc)
      af[qs][kc] = *(const f16x8*)(qh + (size_t)(b*512 + qbase + qs*32 + l31)*128
                                      + kc*16 + 8*lhi);

  // ---- hoist this thread's Wl slice (16 floats) for the B-build
  const int bu  = tid >> 3;    // 0..63 : local u
  const int btc = tid & 7;     // 0..7  : 16-wide t chunk
  const float* wlr = Wl + (size_t)(ubase + bu)*128 + btc*16;
  const float4 wl0 = *(const float4*)(wlr);
  const float4 wl1 = *(const float4*)(wlr+4);
  const float4 wl2 = *(const float4*)(wlr+8);
  const float4 wl3 = *(const float4*)(wlr+12);

  f32x16 acc[2][2];
  #pragma unroll
  for (int i=0;i<16;++i){ acc[0][0][i]=0.f; acc[0][1][i]=0.f;
                          acc[1][0][i]=0.f; acc[1][1][i]=0.f; }

  for (int kki=0; kki<8; ++kki) {
    const int kk = kk0 + kki;
    __syncthreads();                       // Bl / red buffers reusable
    // ---- build Bl[u][t] = Wl[ubase+u][t] * (k*log2e)[b,kk,t]  (f16)
    {
      const float* kp = kls + (size_t)(b*512 + kk)*128 + btc*16;
      const float4 k0 = *(const float4*)(kp);
      const float4 k1 = *(const float4*)(kp+4);
      const float4 k2 = *(const float4*)(kp+8);
      const float4 k3 = *(const float4*)(kp+12);
      f16x8 o0, o1;
      o0[0]=(f16)(wl0.x*k0.x); o0[1]=(f16)(wl0.y*k0.y);
      o0[2]=(f16)(wl0.z*k0.z); o0[3]=(f16)(wl0.w*k0.w);
      o0[4]=(f16)(wl1.x*k1.x); o0[5]=(f16)(wl1.y*k1.y);
      o0[6]=(f16)(wl1.z*k1.z); o0[7]=(f16)(wl1.w*k1.w);
      o1[0]=(f16)(wl2.x*k2.x); o1[1]=(f16)(wl2.y*k2.y);
      o1[2]=(f16)(wl2.z*k2.z); o1[3]=(f16)(wl2.w*k2.w);
      o1[4]=(f16)(wl3.x*k3.x); o1[5]=(f16)(wl3.y*k3.y);
      o1[6]=(f16)(wl3.z*k3.z); o1[7]=(f16)(wl3.w*k3.w);
      *(f16x8*)(&Bl[bu][btc*16])     = o0;
      *(f16x8*)(&Bl[bu][btc*16 + 8]) = o1;
    }
    __syncthreads();

    // ---- MFMA: C[qs][us] = A(64x128) @ B(128x64)
    f32x16 C[2][2];
    #pragma unroll
    for (int i=0;i<16;++i){ C[0][0][i]=0.f; C[0][1][i]=0.f;
                            C[1][0][i]=0.f; C[1][1][i]=0.f; }
    #pragma unroll
    for (int kc=0; kc<8; ++kc) {
      #pragma unroll
      for (int us=0; us<2; ++us) {
        f16x8 bfr = *(const f16x8*)(&Bl[us*32 + l31][kc*16 + 8*lhi]);
        C[0][us] = __builtin_amdgcn_mfma_f32_32x32x16_f16(af[0][kc], bfr, C[0][us], 0,0,0);
        C[1][us] = __builtin_amdgcn_mfma_f32_32x32x16_f16(af[1][kc], bfr, C[1][us], 0,0,0);
      }
    }

    // ---- max over q (per u column): lane -> pair(l^32) -> 8 waves via LDS
    float mx0 = -3.4e38f, mx1 = -3.4e38f;
    #pragma unroll
    for (int qs=0; qs<2; ++qs)
      #pragma unroll
      for (int r=0; r<16; ++r) { mx0 = fmaxf(mx0, C[qs][0][r]);
                                 mx1 = fmaxf(mx1, C[qs][1][r]); }
    mx0 = fmaxf(mx0, __shfl_xor(mx0, 32));
    mx1 = fmaxf(mx1, __shfl_xor(mx1, 32));
    if (lane < 32) { redm[w][lane] = mx0; redm[w][32+lane] = mx1; }
    __syncthreads();
    float M0 = redm[0][l31], M1 = redm[0][32+l31];
    #pragma unroll
    for (int ww=1; ww<8; ++ww) { M0 = fmaxf(M0, redm[ww][l31]);
                                 M1 = fmaxf(M1, redm[ww][32+l31]); }

    // ---- w = y*2^(y-M) in place; accumulate sum|w|
    float s0 = 0.f, s1 = 0.f;
    #pragma unroll
    for (int qs=0; qs<2; ++qs)
      #pragma unroll
      for (int r=0; r<16; ++r) {
        const float y0 = C[qs][0][r], y1 = C[qs][1][r];
        const float t0 = y0 * exp2_fast(y0 - M0);
        const float t1 = y1 * exp2_fast(y1 - M1);
        C[qs][0][r] = t0; C[qs][1][r] = t1;
        s0 += fabsf(t0);  s1 += fabsf(t1);
      }
    s0 += __shfl_xor(s0, 32);
    s1 += __shfl_xor(s1, 32);
    if (lane < 32) { reds[w][lane] = s0; reds[w][32+lane] = s1; }
    __syncthreads();
    float S0 = 0.f, S1 = 0.f;
    #pragma unroll
    for (int ww=0; ww<8; ++ww) { S0 += reds[ww][l31];
                                 S1 += reds[ww][32+l31]; }
    const float v0  = vf[(size_t)(b*512+kk)*128 + ubase + l31];
    const float v1  = vf[(size_t)(b*512+kk)*128 + ubase + 32 + l31];
    const float su0 = v0 / (S0 + LOG2E);   // scale = w/(sum|w| + log2e)
    const float su1 = v1 / (S1 + LOG2E);

    #pragma unroll
    for (int qs=0; qs<2; ++qs)
      #pragma unroll
      for (int r=0; r<16; ++r) {
        acc[qs][0][r] = fmaf(su0, C[qs][0][r], acc[qs][0][r]);
        acc[qs][1][r] = fmaf(su1, C[qs][1][r], acc[qs][1][r]);
      }
  }

  // ---- accumulate this block's 8-kk partial into vsum (f32 atomics, L2)
  #pragma unroll
  for (int qs=0; qs<2; ++qs)
    #pragma unroll
    for (int us=0; us<2; ++us)
      #pragma unroll
      for (int r=0; r<16; ++r) {
        const int q  = qbase + qs*32 + (r&3) + 8*(r>>2) + 4*lhi;
        const int uu = ubase + us*32 + l31;
        atomicAdd(vsum + (size_t)(b*512 + q)*128 + uu, acc[qs][us][r]);
      }
}

// ---------------- K3: out = vsum @ Wo^T ----------------
__global__ __launch_bounds__(256, 2) void k3_out(
    const float* __restrict__ vsum, const float* __restrict__ Wo,
    float* __restrict__ out)
{
  const int sub = blockIdx.x;     // 0..15
  const int b = sub >> 3, rt = sub & 7;
  const int tid = threadIdx.x;
  const int w = tid >> 6, lane = tid & 63;
  const int l31 = lane & 31, lhi = lane >> 5;
  const int rbase = rt*64 + (w>>1)*32;
  const int cbase = (w&1)*64;

  f32x16 C0, C1;
  #pragma unroll
  for (int i=0;i<16;++i){ C0[i]=0.f; C1[i]=0.f; }

  #pragma unroll
  for (int kc=0; kc<8; ++kc) {
    const float* ap = vsum + (size_t)(b*512 + rbase + l31)*128 + kc*16 + 8*lhi;
    f16x8 a = cvt8(*(const float4*)ap, *(const float4*)(ap+4));
    const float* bp0 = Wo + (size_t)(cbase + l31)*128 + kc*16 + 8*lhi;
    f16x8 b0 = cvt8(*(const float4*)bp0, *(const float4*)(bp0+4));
    C0 = __builtin_amdgcn_mfma_f32_32x32x16_f16(a, b0, C0, 0, 0, 0);
    const float* bp1 = bp0 + 32*128;
    f16x8 b1 = cvt8(*(const float4*)bp1, *(const float4*)(bp1+4));
    C1 = __builtin_amdgcn_mfma_f32_32x32x16_f16(a, b1, C1, 0, 0, 0);
  }

  #pragma unroll
  for (int us=0; us<2; ++us)
    #pragma unroll
    for (int r=0; r<16; ++r) {
      const int row = rbase + (r&3) + 8*(r>>2) + 4*lhi;
      const int col = cbase + us*32 + l31;
      out[(size_t)(b*512 + row)*128 + col] = us ? C1[r] : C0[r];
    }
}

extern "C" void kernel_launch(void* const* d_in, const int* in_sizes, int n_in,
                              void* d_out, int out_size, void* d_ws, size_t ws_size,
                              hipStream_t stream) {
  const float* q_tok = (const float*)d_in[0];
  const float* k_tok = (const float*)d_in[1];
  const float* v_tok = (const float*)d_in[2];
  const float* Wk    = (const float*)d_in[3];
  const float* Wq    = (const float*)d_in[4];
  const float* Wv    = (const float*)d_in[5];
  const float* Wl    = (const float*)d_in[6];
  const float* Wo    = (const float*)d_in[7];

  char* ws = (char*)d_ws;
  f16*   qh   = (f16*)  (ws);              // 2*512*128*2 = 262144 B
  float* kls  = (float*)(ws + 262144);     // 2*512*128*4 = 524288 B
  float* vf   = (float*)(ws + 786432);     // 524288 B
  float* vsum = (float*)(ws + 1310720);    // 524288 B

  hipMemsetAsync(vsum, 0, 524288, stream);           // ws is poisoned 0xAA
  k1_proj<<<48, 256, 0, stream>>>(q_tok, k_tok, v_tok, Wq, Wk, Wv, qh, kls, vf);
  k2_main<<<256, 512, 0, stream>>>(qh, kls, vf, Wl, vsum);
  k3_out<<<16, 256, 0, stream>>>(vsum, Wo, (float*)d_out);
}

// Round 3
// 141.877 us; speedup vs baseline: 1.0038x; 1.0038x over previous
//
#include <hip/hip_runtime.h>

// HeadlessAttention: B=2, K=512, Q=512, T=128
//
// k = key@Wk^T; q = query@Wq^T; v = value@Wv^T
// logits[b,kk,q,u] = (Q_hat[b] @ diag(k[b,kk,:]) Wl^T)[q,u]
// swishmax over q (per b,kk,u); out = (sum_kk v[kk,u]*scale) @ Wo^T
//
// Single-pass swishmax (no max-dependency before exp):
//   y = log2e * x  (log2e folded into k at K1)
//   scale = x*exp(x-m)/(sum|.|+1) = y*2^y / (sum_q|y*2^y| + log2e*2^(max y))
// exp2 via __builtin_amdgcn_exp2f (NOT inline asm: TRANS-op result-latency
// hazard must be handled by the compiler's hazard recognizer, which cannot
// see inside an asm() block -- suspected cause of R2's corruption).

using f16    = _Float16;
using f16x8  = __attribute__((ext_vector_type(8)))  f16;
using f32x16 = __attribute__((ext_vector_type(16))) float;

#define LOG2E 1.4426950408889634f

__device__ __forceinline__ float exp2b(float x) {
  return __builtin_amdgcn_exp2f(x);
}

__device__ __forceinline__ f16x8 cvt8(float4 a, float4 b) {
  f16x8 r;
  r[0]=(f16)a.x; r[1]=(f16)a.y; r[2]=(f16)a.z; r[3]=(f16)a.w;
  r[4]=(f16)b.x; r[5]=(f16)b.y; r[6]=(f16)b.z; r[7]=(f16)b.w;
  return r;
}

// ---------------- K1: projections + vsum clear ----------------
__global__ __launch_bounds__(256, 2) void k1_proj(
    const float* __restrict__ q_tok, const float* __restrict__ k_tok,
    const float* __restrict__ v_tok, const float* __restrict__ Wq,
    const float* __restrict__ Wk,    const float* __restrict__ Wv,
    f16* __restrict__ qh, float* __restrict__ kls, float* __restrict__ vf,
    float* __restrict__ vsum)
{
  // vsum clear: 131072 floats = 32768 float4 over 12288 threads
  {
    const int idx = blockIdx.x*256 + threadIdx.x;
    const float4 z = make_float4(0.f,0.f,0.f,0.f);
    for (int j = idx; j < 32768; j += 48*256) ((float4*)vsum)[j] = z;
  }

  const int gid    = blockIdx.x;        // 0..47
  const int tensor = gid >> 4;          // 0=q 1=k 2=v
  const int sub    = gid & 15;
  const int b      = sub >> 3;
  const int rt     = sub & 7;
  const float* X = tensor==0 ? q_tok : (tensor==1 ? k_tok : v_tok);
  const float* W = tensor==0 ? Wq    : (tensor==1 ? Wk    : Wv);

  const int tid = threadIdx.x;
  const int w = tid >> 6, lane = tid & 63;
  const int l31 = lane & 31, lhi = lane >> 5;
  const int rbase = rt*64 + (w>>1)*32;
  const int cbase = (w&1)*64;

  f32x16 C0, C1;
  #pragma unroll
  for (int i=0;i<16;++i){ C0[i]=0.f; C1[i]=0.f; }

  #pragma unroll
  for (int kc=0; kc<8; ++kc) {
    const float* ap = X + (size_t)(b*512 + rbase + l31)*128 + kc*16 + 8*lhi;
    f16x8 a = cvt8(*(const float4*)ap, *(const float4*)(ap+4));
    const float* bp0 = W + (size_t)(cbase + l31)*128 + kc*16 + 8*lhi;
    f16x8 b0 = cvt8(*(const float4*)bp0, *(const float4*)(bp0+4));
    C0 = __builtin_amdgcn_mfma_f32_32x32x16_f16(a, b0, C0, 0, 0, 0);
    const float* bp1 = bp0 + 32*128;
    f16x8 b1 = cvt8(*(const float4*)bp1, *(const float4*)(bp1+4));
    C1 = __builtin_amdgcn_mfma_f32_32x32x16_f16(a, b1, C1, 0, 0, 0);
  }

  #pragma unroll
  for (int us=0; us<2; ++us) {
    #pragma unroll
    for (int r=0; r<16; ++r) {
      const int row = rbase + (r&3) + 8*(r>>2) + 4*lhi;   // verified C/D layout
      const int col = cbase + us*32 + l31;
      const float val = us ? C1[r] : C0[r];
      const size_t idx = (size_t)(b*512 + row)*128 + col;
      if (tensor==0)      qh[idx]  = (f16)val;
      else if (tensor==1) kls[idx] = val * LOG2E;   // fold log2e into k
      else                vf[idx]  = val;
    }
  }
}

// ---------------- K2: fused logits + swishmax + v-scale + K-accumulate ------
// grid 256 = b(2) x u-half(2) x kk-group(64, 8 kk each). 512 thr = 8 waves.
// Two barriers per kk (conservative): B1 after red-write (red + next-Bl
// ready), B2 after acc (all reads of red[cur]/Bl[cur] retired).
__global__ __launch_bounds__(512, 2) void k2_main(
    const f16* __restrict__ qh, const float* __restrict__ kls,
    const float* __restrict__ vf, const float* __restrict__ Wl,
    float* __restrict__ vsum)
{
  const int gid  = blockIdx.x;          // 0..255
  const int b    = gid >> 7;
  const int half = (gid >> 6) & 1;
  const int grp  = gid & 63;
  const int kk0  = grp * 8;

  const int tid = threadIdx.x;
  const int w = tid >> 6, lane = tid & 63;
  const int l31 = lane & 31, lhi = lane >> 5;
  const int ubase = half * 64;
  const int qbase = w * 64;

  __shared__ f16    Bl[2][64][136];     // [u][t] scaled Wl, +8 pad
  __shared__ float2 red[2][8][64];      // (max, sum) per wave x col, dbuf

  // per-thread Wl slice (16 floats) for the B-build, register-resident
  const int bu  = tid >> 3;    // 0..63 : local u
  const int btc = tid & 7;     // 0..7  : 16-wide t chunk
  const float* wlr = Wl + (size_t)(ubase + bu)*128 + btc*16;
  const float4 wl0 = *(const float4*)(wlr);
  const float4 wl1 = *(const float4*)(wlr+4);
  const float4 wl2 = *(const float4*)(wlr+8);
  const float4 wl3 = *(const float4*)(wlr+12);

  const float* kbase = kls + (size_t)(b*512 + kk0)*128 + btc*16;
  const f16*   abase = qh  + (size_t)(b*512 + qbase + l31)*128 + 8*lhi;
  const float* vbase = vf  + (size_t)(b*512 + kk0)*128 + ubase;

  f32x16 acc[2][2];
  #pragma unroll
  for (int i=0;i<16;++i){ acc[0][0][i]=0.f; acc[0][1][i]=0.f;
                          acc[1][0][i]=0.f; acc[1][1][i]=0.f; }

  // prologue: build Bl[0] for kk0; prefetch k-row kk0+1
  {
    const float4 k0 = *(const float4*)(kbase);
    const float4 k1 = *(const float4*)(kbase+4);
    const float4 k2 = *(const float4*)(kbase+8);
    const float4 k3 = *(const float4*)(kbase+12);
    float4 a0 = make_float4(wl0.x*k0.x, wl0.y*k0.y, wl0.z*k0.z, wl0.w*k0.w);
    float4 a1 = make_float4(wl1.x*k1.x, wl1.y*k1.y, wl1.z*k1.z, wl1.w*k1.w);
    float4 a2 = make_float4(wl2.x*k2.x, wl2.y*k2.y, wl2.z*k2.z, wl2.w*k2.w);
    float4 a3 = make_float4(wl3.x*k3.x, wl3.y*k3.y, wl3.z*k3.z, wl3.w*k3.w);
    *(f16x8*)(&Bl[0][bu][btc*16])     = cvt8(a0, a1);
    *(f16x8*)(&Bl[0][bu][btc*16 + 8]) = cvt8(a2, a3);
  }
  float4 n0 = *(const float4*)(kbase+128);
  float4 n1 = *(const float4*)(kbase+132);
  float4 n2 = *(const float4*)(kbase+136);
  float4 n3 = *(const float4*)(kbase+140);
  __syncthreads();

  for (int i=0; i<8; ++i) {
    const int cur = i & 1;

    const float v0 = vbase[i*128 + l31];
    const float v1 = vbase[i*128 + 32 + l31];

    // build next B-tile (overlaps MFMA below in the wave schedule)
    if (i < 7) {
      float4 a0 = make_float4(wl0.x*n0.x, wl0.y*n0.y, wl0.z*n0.z, wl0.w*n0.w);
      float4 a1 = make_float4(wl1.x*n1.x, wl1.y*n1.y, wl1.z*n1.z, wl1.w*n1.w);
      float4 a2 = make_float4(wl2.x*n2.x, wl2.y*n2.y, wl2.z*n2.z, wl2.w*n2.w);
      float4 a3 = make_float4(wl3.x*n3.x, wl3.y*n3.y, wl3.z*n3.z, wl3.w*n3.w);
      *(f16x8*)(&Bl[cur^1][bu][btc*16])     = cvt8(a0, a1);
      *(f16x8*)(&Bl[cur^1][bu][btc*16 + 8]) = cvt8(a2, a3);
      if (i < 6) {
        const float* kp = kbase + (i+2)*128;
        n0 = *(const float4*)(kp);   n1 = *(const float4*)(kp+4);
        n2 = *(const float4*)(kp+8); n3 = *(const float4*)(kp+12);
      }
    }

    // MFMA: C[qs][us] = A(64x128) @ B(128x64)
    f32x16 C[2][2];
    #pragma unroll
    for (int j=0;j<16;++j){ C[0][0][j]=0.f; C[0][1][j]=0.f;
                            C[1][0][j]=0.f; C[1][1][j]=0.f; }
    #pragma unroll
    for (int kc=0; kc<8; ++kc) {
      f16x8 a0 = *(const f16x8*)(abase + kc*16);
      f16x8 a1 = *(const f16x8*)(abase + 32*128 + kc*16);
      #pragma unroll
      for (int us=0; us<2; ++us) {
        f16x8 bfr = *(const f16x8*)(&Bl[cur][us*32 + l31][kc*16 + 8*lhi]);
        C[0][us] = __builtin_amdgcn_mfma_f32_32x32x16_f16(a0, bfr, C[0][us], 0,0,0);
        C[1][us] = __builtin_amdgcn_mfma_f32_32x32x16_f16(a1, bfr, C[1][us], 0,0,0);
      }
    }

    // single pass: p = y*2^y (no max needed), track max(y) and sum|p|
    float mx0a=-3.4e38f, mx0b=-3.4e38f, mx1a=-3.4e38f, mx1b=-3.4e38f;
    float s0a=0.f, s0b=0.f, s1a=0.f, s1b=0.f;
    #pragma unroll
    for (int qs=0; qs<2; ++qs)
      #pragma unroll
      for (int r=0; r<16; ++r) {
        const float y0 = C[qs][0][r], y1 = C[qs][1][r];
        const float p0 = y0 * exp2b(y0);
        const float p1 = y1 * exp2b(y1);
        C[qs][0][r] = p0; C[qs][1][r] = p1;
        if (r & 1) { mx0b=fmaxf(mx0b,y0); s0b+=fabsf(p0);
                     mx1b=fmaxf(mx1b,y1); s1b+=fabsf(p1); }
        else       { mx0a=fmaxf(mx0a,y0); s0a+=fabsf(p0);
                     mx1a=fmaxf(mx1a,y1); s1a+=fabsf(p1); }
      }
    float mx0 = fmaxf(mx0a,mx0b), mx1 = fmaxf(mx1a,mx1b);
    float sm0 = s0a+s0b,          sm1 = s1a+s1b;
    mx0 = fmaxf(mx0, __shfl_xor(mx0, 32));
    mx1 = fmaxf(mx1, __shfl_xor(mx1, 32));
    sm0 += __shfl_xor(sm0, 32);
    sm1 += __shfl_xor(sm1, 32);
    red[cur][w][lane] = lhi ? make_float2(mx1, sm1) : make_float2(mx0, sm0);

    __syncthreads();   // B1: red[cur] ready; Bl[cur^1] fully written

    float M0=-3.4e38f, S0=0.f, M1=-3.4e38f, S1=0.f;
    #pragma unroll
    for (int ww=0; ww<8; ++ww) {
      const float2 t0 = red[cur][ww][l31];
      const float2 t1 = red[cur][ww][32+l31];
      M0 = fmaxf(M0, t0.x); S0 += t0.y;
      M1 = fmaxf(M1, t1.x); S1 += t1.y;
    }
    const float su0 = v0 / (S0 + LOG2E * exp2b(M0));
    const float su1 = v1 / (S1 + LOG2E * exp2b(M1));

    #pragma unroll
    for (int qs=0; qs<2; ++qs)
      #pragma unroll
      for (int r=0; r<16; ++r) {
        acc[qs][0][r] = fmaf(su0, C[qs][0][r], acc[qs][0][r]);
        acc[qs][1][r] = fmaf(su1, C[qs][1][r], acc[qs][1][r]);
      }

    __syncthreads();   // B2: all reads of red[cur]/Bl[cur] retired
  }

  // accumulate this block's 8-kk partial into vsum (f32 atomics, L2)
  #pragma unroll
  for (int qs=0; qs<2; ++qs)
    #pragma unroll
    for (int us=0; us<2; ++us)
      #pragma unroll
      for (int r=0; r<16; ++r) {
        const int q  = qbase + qs*32 + (r&3) + 8*(r>>2) + 4*lhi;
        const int uu = ubase + us*32 + l31;
        atomicAdd(vsum + (size_t)(b*512 + q)*128 + uu, acc[qs][us][r]);
      }
}

// ---------------- K3: out = vsum @ Wo^T ----------------
__global__ __launch_bounds__(256, 2) void k3_out(
    const float* __restrict__ vsum, const float* __restrict__ Wo,
    float* __restrict__ out)
{
  const int sub = blockIdx.x;     // 0..15
  const int b = sub >> 3, rt = sub & 7;
  const int tid = threadIdx.x;
  const int w = tid >> 6, lane = tid & 63;
  const int l31 = lane & 31, lhi = lane >> 5;
  const int rbase = rt*64 + (w>>1)*32;
  const int cbase = (w&1)*64;

  f32x16 C0, C1;
  #pragma unroll
  for (int i=0;i<16;++i){ C0[i]=0.f; C1[i]=0.f; }

  #pragma unroll
  for (int kc=0; kc<8; ++kc) {
    const float* ap = vsum + (size_t)(b*512 + rbase + l31)*128 + kc*16 + 8*lhi;
    f16x8 a = cvt8(*(const float4*)ap, *(const float4*)(ap+4));
    const float* bp0 = Wo + (size_t)(cbase + l31)*128 + kc*16 + 8*lhi;
    f16x8 b0 = cvt8(*(const float4*)bp0, *(const float4*)(bp0+4));
    C0 = __builtin_amdgcn_mfma_f32_32x32x16_f16(a, b0, C0, 0, 0, 0);
    const float* bp1 = bp0 + 32*128;
    f16x8 b1 = cvt8(*(const float4*)bp1, *(const float4*)(bp1+4));
    C1 = __builtin_amdgcn_mfma_f32_32x32x16_f16(a, b1, C1, 0, 0, 0);
  }

  #pragma unroll
  for (int us=0; us<2; ++us)
    #pragma unroll
    for (int r=0; r<16; ++r) {
      const int row = rbase + (r&3) + 8*(r>>2) + 4*lhi;
      const int col = cbase + us*32 + l31;
      out[(size_t)(b*512 + row)*128 + col] = us ? C1[r] : C0[r];
    }
}

extern "C" void kernel_launch(void* const* d_in, const int* in_sizes, int n_in,
                              void* d_out, int out_size, void* d_ws, size_t ws_size,
                              hipStream_t stream) {
  const float* q_tok = (const float*)d_in[0];
  const float* k_tok = (const float*)d_in[1];
  const float* v_tok = (const float*)d_in[2];
  const float* Wk    = (const float*)d_in[3];
  const float* Wq    = (const float*)d_in[4];
  const float* Wv    = (const float*)d_in[5];
  const float* Wl    = (const float*)d_in[6];
  const float* Wo    = (const float*)d_in[7];

  char* ws = (char*)d_ws;
  f16*   qh   = (f16*)  (ws);              // 2*512*128*2 = 262144 B
  float* kls  = (float*)(ws + 262144);     // 524288 B
  float* vf   = (float*)(ws + 786432);     // 524288 B
  float* vsum = (float*)(ws + 1310720);    // 524288 B  (cleared by K1)

  k1_proj<<<48, 256, 0, stream>>>(q_tok, k_tok, v_tok, Wq, Wk, Wv, qh, kls, vf, vsum);
  k2_main<<<256, 512, 0, stream>>>(qh, kls, vf, Wl, vsum);
  k3_out<<<16, 256, 0, stream>>>(vsum, Wo, (float*)d_out);
}